// Round 7
// baseline (450.119 us; speedup 1.0000x reference)
//
#include <hip/hip_runtime.h>
#include <hip/hip_bf16.h>
#include <stdint.h>

// Attention_48241072668890: x@Wq^T -> flash-attn over fp32 KV cache -> @Wo^T
// R7: attn 512-thread blocks (8 waves x 16 q-rows, was 4 x 32): same 80KB LDS,
// same 512-block grid, but 16 waves/CU instead of 8 — doubles latency hiding
// (R6 was occupancy-capped at 2 blocks/CU x 4 waves). Per-wave state halves
// -> fits the 128-VGPR cap of launch_bounds(512,4). Mask loads moved inside
// the (rare) mflag branch — stage gl_lds are the only hot-path VMEM now.
// Keeps R6 mask gating + XCD remaps + GEMM swizzle.

#define DIM   4096
#define NH    32
#define HD    128
#define BB    2
#define SS    1024
#define CC    2048

typedef __bf16 bf16x8 __attribute__((ext_vector_type(8)));
typedef float  f32x4  __attribute__((ext_vector_type(4)));

__device__ __forceinline__ unsigned short f2bf(float f) {
  union { __hip_bfloat16 h; unsigned short u; } cv;
  cv.h = __float2bfloat16(f);
  return cv.u;
}

__device__ __forceinline__ void gl_lds16(const void* g, void* l) {
  __builtin_amdgcn_global_load_lds(
      (__attribute__((address_space(1))) void*)(uintptr_t)(g),
      (__attribute__((address_space(3))) void*)(l), 16, 0, 0);
}

// ---------------- converts ----------------
__global__ void conv_f32_bf16(const float* __restrict__ in, unsigned short* __restrict__ out, int n4) {
  int i = blockIdx.x * blockDim.x + threadIdx.x;
  int stride = gridDim.x * blockDim.x;
  for (; i < n4; i += stride) {
    float4 v = reinterpret_cast<const float4*>(in)[i];
    ushort4 o;
    o.x = f2bf(v.x); o.y = f2bf(v.y); o.z = f2bf(v.z); o.w = f2bf(v.w);
    reinterpret_cast<ushort4*>(out)[i] = o;
  }
}

// cache_k [B,C,NH,HD] f32 -> [B*NH, C, HD] bf16 (head-major gather)
__global__ void conv_k(const float* __restrict__ in, unsigned short* __restrict__ out) {
  const int total4 = BB * NH * CC * HD / 4;
  int i = blockIdx.x * blockDim.x + threadIdx.x;
  int stride = gridDim.x * blockDim.x;
  for (; i < total4; i += stride) {
    size_t o = (size_t)i * 4;
    int d   = (int)(o & (HD - 1));
    size_t r = o >> 7;                 // (b*NH+h)*CC + c
    int c   = (int)(r & (CC - 1));
    int bh  = (int)(r >> 11);
    int hh = bh & (NH - 1), bb = bh >> 5;
    float4 v = *reinterpret_cast<const float4*>(in + ((size_t)(bb * CC + c) * NH + hh) * HD + d);
    ushort4 u; u.x = f2bf(v.x); u.y = f2bf(v.y); u.z = f2bf(v.z); u.w = f2bf(v.w);
    *reinterpret_cast<ushort4*>(out + o) = u;
  }
}

// cache_v [B,C,NH,HD] f32 -> [B*NH, HD, C] bf16 (transposed per head, LDS tile)
__global__ void conv_v_t(const float* __restrict__ in, unsigned short* __restrict__ out) {
  __shared__ float tile[32][33];
  const int c0 = blockIdx.x * 32, d0 = blockIdx.y * 32;
  const int bh = blockIdx.z;
  const int hh = bh & (NH - 1), bb = bh >> 5;
  const int tx = threadIdx.x, ty = threadIdx.y;   // 32 x 8
#pragma unroll
  for (int i = 0; i < 4; ++i) {
    int c = c0 + ty + i * 8;
    tile[ty + i * 8][tx] = in[((size_t)(bb * CC + c) * NH + hh) * HD + d0 + tx];
  }
  __syncthreads();
#pragma unroll
  for (int i = 0; i < 4; ++i) {
    int d = d0 + ty + i * 8;
    out[((size_t)bh * HD + d) * CC + c0 + tx] = f2bf(tile[tx][ty + i * 8]);
  }
}

// ---------------- mask nonzero flags: flag[qt*32+ct] = any(mask tile != 0) ----
__global__ void mask_flags(const float* __restrict__ mask, int* __restrict__ flags) {
  __shared__ int s[4];
  const int qt = blockIdx.x >> 5, ct = blockIdx.x & 31;
  const int t = threadIdx.x, w = t >> 6;
  const float4* m4 = (const float4*)mask;
  int nz = 0;
#pragma unroll
  for (int i = 0; i < 8; ++i) {
    int idx = i * 256 + t;              // 2048 float4 per 128x64 tile
    int row = idx >> 4, c4 = idx & 15;
    float4 v = m4[(size_t)(qt * 128 + row) * (CC / 4) + ct * 16 + c4];
    nz |= (v.x != 0.f) | (v.y != 0.f) | (v.z != 0.f) | (v.w != 0.f);
  }
  int wa = (int)__any(nz);
  if ((t & 63) == 0) s[w] = wa;
  __syncthreads();
  if (t == 0) flags[qt * 32 + ct] = s[0] | s[1] | s[2] | s[3];
}

// ---------------- GEMM: C[M,N] = A[M,K] * B[N,K]^T  (m97 structure + T1) ------
template <int OUT_BF16>
__global__ __launch_bounds__(256, 2) void gemm_bt(
    const unsigned short* __restrict__ A,
    const unsigned short* __restrict__ Bw,
    void* __restrict__ Cout,
    int M, int N, int K, float scale)
{
  __shared__ __align__(16) unsigned short As[128 * 32];
  __shared__ __align__(16) unsigned short Bs[128 * 32];
  const int t = threadIdx.x;
  const int w = t >> 6, lane = t & 63;
  const int wr = w >> 1, wc = w & 1;
  // XCD-chunked swizzle (nwg % 8 == 0 here -> bijective)
  const int nwg  = gridDim.x * gridDim.y;
  const int flat = blockIdx.y * gridDim.x + blockIdx.x;
  const int swzb = (flat & 7) * (nwg >> 3) + (flat >> 3);
  const int bm0 = (swzb / gridDim.x) * 128, bn0 = (swzb % gridDim.x) * 128;

  const unsigned short* aSrc = A  + (size_t)(bm0 + (t >> 2)) * K + (t & 3) * 8;
  const unsigned short* bSrc = Bw + (size_t)(bn0 + (t >> 2)) * K + (t & 3) * 8;
  char* aDst = (char*)As + w * 1024;
  char* bDst = (char*)Bs + w * 1024;
  const size_t half = (size_t)64 * K;

  f32x4 acc[4][4];
#pragma unroll
  for (int m = 0; m < 4; ++m)
#pragma unroll
    for (int n = 0; n < 4; ++n) acc[m][n] = (f32x4){0.f, 0.f, 0.f, 0.f};

  for (int k0 = 0; k0 < K; k0 += 32) {
    gl_lds16(aSrc,        aDst);
    gl_lds16(aSrc + half, aDst + 4096);
    gl_lds16(bSrc,        bDst);
    gl_lds16(bSrc + half, bDst + 4096);
    aSrc += 32; bSrc += 32;
    __syncthreads();

    bf16x8 af[4], bf[4];
#pragma unroll
    for (int m = 0; m < 4; ++m)
      af[m] = *(const bf16x8*)&As[(wr * 64 + m * 16 + (lane & 15)) * 32 + (lane >> 4) * 8];
#pragma unroll
    for (int n = 0; n < 4; ++n)
      bf[n] = *(const bf16x8*)&Bs[(wc * 64 + n * 16 + (lane & 15)) * 32 + (lane >> 4) * 8];
#pragma unroll
    for (int m = 0; m < 4; ++m)
#pragma unroll
      for (int n = 0; n < 4; ++n)
        acc[m][n] = __builtin_amdgcn_mfma_f32_16x16x32_bf16(af[m], bf[n], acc[m][n], 0, 0, 0);
    __syncthreads();
  }

  const int r0 = (lane >> 4) * 4, cl = lane & 15;
#pragma unroll
  for (int m = 0; m < 4; ++m) {
#pragma unroll
    for (int n = 0; n < 4; ++n) {
      int row = bm0 + wr * 64 + m * 16 + r0;
      int col = bn0 + wc * 64 + n * 16 + cl;
#pragma unroll
      for (int r = 0; r < 4; ++r) {
        float v = acc[m][n][r] * scale;
        if (OUT_BF16) ((unsigned short*)Cout)[(size_t)(row + r) * N + col] = f2bf(v);
        else          ((float*)Cout)[(size_t)(row + r) * N + col] = v;
      }
    }
  }
}

// ---------------- flash attention ----------------
// QT=128 (8 waves x 16 rows), KT=64, double-buffered K/V, log2-domain softmax,
// T13 defer-max, per-tile mask gating, XCD-chunked block remap.
// 512 threads, LDS 80KB -> 2 blocks/CU = 16 waves/CU. VGPR must be <=128.
__global__ __launch_bounds__(512, 4) void attn_fwd(
    const unsigned short* __restrict__ Qb,
    const unsigned short* __restrict__ Kb,
    const unsigned short* __restrict__ Vtb,
    const float* __restrict__ mask,
    const int* __restrict__ Mf,
    unsigned short* __restrict__ Ob)
{
  __shared__ __align__(16) unsigned short Ks[2][64 * 128];   // 16KB x2
  __shared__ __align__(16) unsigned short Vs[2][64 * 128];   // logical [128][64] x2
  __shared__ __align__(16) unsigned short Ps[8][16 * 64];    // 2KB/wave

  const int t = threadIdx.x, w = t >> 6, lane = t & 63;
  const int lg = (blockIdx.x & 7) * 64 + (blockIdx.x >> 3);  // XCD-chunked remap
  const int qt = lg & 7, bh = lg >> 3;
  const int hh = bh & (NH - 1), bb = bh >> 5;
  const int q0 = qt * 128;
  const int l15 = lane & 15, g = lane >> 4;
  const int rb4 = g * 4;

  // Q fragments in registers (A-frag: row = lane&15, k = kk*32 + g*8)
  bf16x8 qf[4];
  {
    const unsigned short* qp = Qb + ((size_t)(bb * SS + q0 + w * 16 + l15)) * DIM
                               + hh * HD + g * 8;
#pragma unroll
    for (int kk = 0; kk < 4; ++kk)
      qf[kk] = *(const bf16x8*)(qp + kk * 32);
  }

  // staging sources (pre-swizzled global so linear LDS dest carries the XOR)
  const unsigned short* kSrc = Kb + ((size_t)bh * CC + (t >> 4)) * HD
                               + (((t & 15) ^ ((t >> 4) & 7)) * 8);   // rows 0..31
  const unsigned short* vSrc = Vtb + ((size_t)bh * HD + (t >> 3)) * CC
                               + (((t & 7) ^ ((t >> 3) & 7)) * 8);    // d-rows 0..63

  f32x4 acc_o[8];
#pragma unroll
  for (int i = 0; i < 8; ++i) acc_o[i] = (f32x4){0.f, 0.f, 0.f, 0.f};
  float m_run[4], l_run[4];
#pragma unroll
  for (int r = 0; r < 4; ++r) { m_run[r] = -1e30f; l_run[r] = 0.f; }

  const int swz = (lane & 7) << 3;
  const float LOG2E = 1.4426950408889634f;

  // prologue: stage tile 0 into buffer 0 (512 thr x 16B = 8KB per issue)
  int mflag = Mf[qt * 32];
  {
    char* kd = (char*)Ks[0] + w * 1024;
    char* vd = (char*)Vs[0] + w * 1024;
#pragma unroll
    for (int i = 0; i < 2; ++i) {
      gl_lds16(kSrc + (size_t)(i * 32) * HD, kd + i * 8192);
      gl_lds16(vSrc + (size_t)i * 64 * CC,   vd + i * 8192);
    }
  }
  __syncthreads();

  int cur = 0;
  for (int c0 = 0; c0 < CC; c0 += 64) {
    const int ct = c0 >> 6;
    int nextFlag = (ct < 31) ? Mf[qt * 32 + ct + 1] : 0;

    // stage NEXT tile — only hot-path VMEM; latency hides under whole tile
    if (c0 + 64 < CC) {
      char* kd = (char*)Ks[cur ^ 1] + w * 1024;
      char* vd = (char*)Vs[cur ^ 1] + w * 1024;
#pragma unroll
      for (int i = 0; i < 2; ++i) {
        gl_lds16(kSrc + (size_t)(c0 + 64 + i * 32) * HD, kd + i * 8192);
        gl_lds16(vSrc + (size_t)i * 64 * CC + c0 + 64,   vd + i * 8192);
      }
    }
    __builtin_amdgcn_sched_barrier(0);

    // QK^T: 16 q-rows x 64 c-cols
    f32x4 sc[4];
#pragma unroll
    for (int nf = 0; nf < 4; ++nf) sc[nf] = (f32x4){0.f, 0.f, 0.f, 0.f};
    __builtin_amdgcn_s_setprio(1);
#pragma unroll
    for (int kk = 0; kk < 4; ++kk) {
#pragma unroll
      for (int nf = 0; nf < 4; ++nf) {
        bf16x8 kf = *(const bf16x8*)&Ks[cur][((nf * 16 + l15) * 128 + kk * 32 + g * 8) ^ swz];
        sc[nf] = __builtin_amdgcn_mfma_f32_16x16x32_bf16(qf[kk], kf, sc[nf], 0, 0, 0);
      }
    }
    __builtin_amdgcn_s_setprio(0);

    // + mask (log2 domain) — rare path; loads only when tile mask nonzero
    if (mflag) {
#pragma unroll
      for (int nf = 0; nf < 4; ++nf)
#pragma unroll
        for (int r = 0; r < 4; ++r)
          sc[nf][r] = fmaf(mask[(size_t)(q0 + w * 16 + rb4 + r) * CC + c0 + nf * 16 + l15],
                           LOG2E, sc[nf][r]);
    }

    // softmax (log2 domain, T13 defer-max)
    int ok = 1;
    float pm[4];
#pragma unroll
    for (int r = 0; r < 4; ++r) {
      pm[r] = fmaxf(fmaxf(sc[0][r], sc[1][r]), fmaxf(sc[2][r], sc[3][r]));
      ok = ok && (pm[r] <= m_run[r] + 8.0f);
    }
    if (!__all(ok)) {
#pragma unroll
      for (int r = 0; r < 4; ++r) {
        float mx = pm[r];
#pragma unroll
        for (int d = 1; d < 16; d <<= 1)
          mx = fmaxf(mx, __shfl_xor(mx, d));
        float mn = fmaxf(m_run[r], mx);
        float corr = __builtin_amdgcn_exp2f(m_run[r] - mn);
        m_run[r] = mn;
        l_run[r] *= corr;
#pragma unroll
        for (int nd = 0; nd < 8; ++nd) acc_o[nd][r] *= corr;
      }
    }

    // p = exp2(sc - m); per-lane partial l; P -> LDS bf16 (swizzled, per-wave)
#pragma unroll
    for (int r = 0; r < 4; ++r) {
      int rw = rb4 + r;
      int rsw = (rw & 7) << 3;
#pragma unroll
      for (int nf = 0; nf < 4; ++nf) {
        float p = __builtin_amdgcn_exp2f(sc[nf][r] - m_run[r]);
        l_run[r] += p;
        Ps[w][rw * 64 + ((nf * 16 + l15) ^ rsw)] = f2bf(p);
      }
    }

    // PV: acc_o[nd] += P[16x64] * V[64 x 128]
    __builtin_amdgcn_s_setprio(1);
#pragma unroll
    for (int kk = 0; kk < 2; ++kk) {
      bf16x8 pf = *(const bf16x8*)&Ps[w][(l15 * 64 + kk * 32 + g * 8) ^ swz];
#pragma unroll
      for (int nd = 0; nd < 8; ++nd) {
        bf16x8 vf = *(const bf16x8*)&Vs[cur][((nd * 16 + l15) * 64 + kk * 32 + g * 8) ^ swz];
        acc_o[nd] = __builtin_amdgcn_mfma_f32_16x16x32_bf16(pf, vf, acc_o[nd], 0, 0, 0);
      }
    }
    __builtin_amdgcn_s_setprio(0);
    __syncthreads();
    cur ^= 1;
    mflag = nextFlag;
  }

  // epilogue: reduce per-lane partial l across the 16-lane row group, then O/l
#pragma unroll
  for (int r = 0; r < 4; ++r)
#pragma unroll
    for (int d = 1; d < 16; d <<= 1)
      l_run[r] += __shfl_xor(l_run[r], d);

#pragma unroll
  for (int nd = 0; nd < 8; ++nd)
#pragma unroll
    for (int r = 0; r < 4; ++r) {
      float v = acc_o[nd][r] / l_run[r];
      int row = q0 + w * 16 + rb4 + r;
      Ob[(size_t)(bb * SS + row) * DIM + hh * HD + nd * 16 + l15] = f2bf(v);
    }
}

// ---------------- launch ----------------
extern "C" void kernel_launch(void* const* d_in, const int* in_sizes, int n_in,
                              void* d_out, int out_size, void* d_ws, size_t ws_size,
                              hipStream_t stream) {
  const float* x       = (const float*)d_in[0];
  const float* mask    = (const float*)d_in[2];   // [1,1,S,C]
  const float* cache_k = (const float*)d_in[4];   // [B,C,NH,HD]
  const float* cache_v = (const float*)d_in[5];
  const float* wq      = (const float*)d_in[6];   // [DIM,DIM]
  const float* wo      = (const float*)d_in[9];
  float* out = (float*)d_out;

  // workspace layout (128 MiB):
  char* ws = (char*)d_ws;
  unsigned short* Wbf  = (unsigned short*)(ws);                                  // 32 MiB (wq, later wo)
  unsigned short* xbf  = (unsigned short*)(ws + 33554432);                       // 16 MiB (x, later attn-out)
  unsigned short* qbf  = (unsigned short*)(ws + 33554432 + 16777216);            // 16 MiB
  unsigned short* kbf  = (unsigned short*)(ws + 33554432 + 2 * 16777216);        // 32 MiB
  unsigned short* vtbf = (unsigned short*)(ws + 2 * 33554432 + 2 * 16777216);    // 32 MiB
  // mask flags (1 KiB) at the head of d_out — final gemm overwrites all of
  // d_out afterwards, so no stale state leaks across replays.
  int* mflags = (int*)d_out;

  conv_f32_bf16<<<2048, 256, 0, stream>>>(x,  xbf, BB * SS * DIM / 4);
  conv_f32_bf16<<<2048, 256, 0, stream>>>(wq, Wbf, DIM * DIM / 4);
  dim3 gg(DIM / 128, (BB * SS) / 128);
  // scale = (1/sqrt(128)) * log2(e) — softmax runs in log2 domain
  gemm_bt<1><<<gg, 256, 0, stream>>>(xbf, Wbf, qbf, BB * SS, DIM, DIM, 0.12751744682f);
  conv_k<<<2048, 256, 0, stream>>>(cache_k, kbf);
  conv_v_t<<<dim3(CC / 32, HD / 32, BB * NH), dim3(32, 8, 1), 0, stream>>>(cache_v, vtbf);
  mask_flags<<<256, 256, 0, stream>>>(mask, mflags);
  attn_fwd<<<BB * NH * 8, 512, 0, stream>>>(qbf, kbf, vtbf, mask, mflags, xbf);
  conv_f32_bf16<<<2048, 256, 0, stream>>>(wo, Wbf, DIM * DIM / 4);
  gemm_bt<0><<<gg, 256, 0, stream>>>(xbf, Wbf, out, BB * SS, DIM, DIM, 1.0f);
}

// Round 8
// 381.514 us; speedup vs baseline: 1.1798x; 1.1798x over previous
//
#include <hip/hip_runtime.h>
#include <hip/hip_bf16.h>
#include <stdint.h>

// Attention_48241072668890: x@Wq^T -> flash-attn over fp32 KV cache -> @Wo^T
// R8: (1) attn reverted to R6 exactly (R7's 512-thr/(512,4) spilled: VGPR
// capped 64, 47MB/dispatch scratch writes). (2) all 5 independent prep ops
// (x-conv, wq-conv, k-conv, v-transpose, mask-flags) merged into ONE kernel
// (block-range dispatch) — kills 4 launch gaps + overlaps transpose latency
// with streaming converts. Kernels: prep, gemmQ, attn, wo-conv, gemmO.

#define DIM   4096
#define NH    32
#define HD    128
#define BB    2
#define SS    1024
#define CC    2048

typedef __bf16 bf16x8 __attribute__((ext_vector_type(8)));
typedef float  f32x4  __attribute__((ext_vector_type(4)));

__device__ __forceinline__ unsigned short f2bf(float f) {
  union { __hip_bfloat16 h; unsigned short u; } cv;
  cv.h = __float2bfloat16(f);
  return cv.u;
}

__device__ __forceinline__ void gl_lds16(const void* g, void* l) {
  __builtin_amdgcn_global_load_lds(
      (__attribute__((address_space(1))) void*)(uintptr_t)(g),
      (__attribute__((address_space(3))) void*)(l), 16, 0, 0);
}

// ---------------- wo convert (runs post-attn; Wbf buffer reused) ----------
__global__ void conv_f32_bf16(const float* __restrict__ in, unsigned short* __restrict__ out, int n4) {
  int i = blockIdx.x * blockDim.x + threadIdx.x;
  int stride = gridDim.x * blockDim.x;
  for (; i < n4; i += stride) {
    float4 v = reinterpret_cast<const float4*>(in)[i];
    ushort4 o;
    o.x = f2bf(v.x); o.y = f2bf(v.y); o.z = f2bf(v.z); o.w = f2bf(v.w);
    reinterpret_cast<ushort4*>(out)[i] = o;
  }
}

// ---------------- merged prep: x-conv | wq-conv | k-conv | v^T | mask flags --
// blocks [0,1024): x f32->bf16            (2.09M float4, 8/thread)
// blocks [1024,3072): wq f32->bf16        (4.19M float4, 8/thread)
// blocks [3072,5120): cache_k gather      (4.19M float4, 8/thread)
// blocks [5120,9216): cache_v 64x64 transpose tiles
// blocks [9216,9472): mask nonzero flags (128q x 64c granularity)
__global__ __launch_bounds__(256) void prep(
    const float* __restrict__ x,   unsigned short* __restrict__ xbf,
    const float* __restrict__ wq,  unsigned short* __restrict__ wbf,
    const float* __restrict__ ck,  unsigned short* __restrict__ kbf,
    const float* __restrict__ cv,  unsigned short* __restrict__ vtbf,
    const float* __restrict__ mask, int* __restrict__ flags)
{
  const int b = blockIdx.x, t = threadIdx.x;

  if (b < 3072) {                 // straight f32->bf16 converts (x, wq)
    const float* in; unsigned short* out; int base, nthr;
    if (b < 1024) { in = x;  out = xbf; base = b;        nthr = 1024 * 256; }
    else          { in = wq; out = wbf; base = b - 1024; nthr = 2048 * 256; }
    int n4 = (b < 1024) ? (BB * SS * DIM / 4) : (DIM * DIM / 4);
    for (int i = base * 256 + t; i < n4; i += nthr) {
      float4 v = reinterpret_cast<const float4*>(in)[i];
      ushort4 o;
      o.x = f2bf(v.x); o.y = f2bf(v.y); o.z = f2bf(v.z); o.w = f2bf(v.w);
      reinterpret_cast<ushort4*>(out)[i] = o;
    }
  } else if (b < 5120) {          // cache_k [B,C,NH,HD] -> [B*NH,C,HD] bf16
    const int total4 = BB * NH * CC * HD / 4;
    for (int i = (b - 3072) * 256 + t; i < total4; i += 2048 * 256) {
      size_t o = (size_t)i * 4;
      int d  = (int)(o & (HD - 1));
      size_t r = o >> 7;
      int c  = (int)(r & (CC - 1));
      int bh = (int)(r >> 11);
      int hh = bh & (NH - 1), bb = bh >> 5;
      float4 v = *reinterpret_cast<const float4*>(ck + ((size_t)(bb * CC + c) * NH + hh) * HD + d);
      ushort4 u; u.x = f2bf(v.x); u.y = f2bf(v.y); u.z = f2bf(v.z); u.w = f2bf(v.w);
      *reinterpret_cast<ushort4*>(kbf + o) = u;
    }
  } else if (b < 9216) {          // cache_v [B,C,NH,HD] -> [B*NH,HD,C] bf16
    __shared__ float tile[64][65];
    const int e  = b - 5120;
    const int ct = e & 31, rest = e >> 5;
    const int dt = rest & 1, bh = rest >> 1;
    const int hh = bh & (NH - 1), bb = bh >> 5;
    const int c0 = ct * 64, d0 = dt * 64;
    const int tx = t & 63, ty = t >> 6;           // 64 x 4
#pragma unroll
    for (int i = 0; i < 16; ++i) {
      int cl = ty + i * 4;
      tile[cl][tx] = cv[((size_t)(bb * CC + c0 + cl) * NH + hh) * HD + d0 + tx];
    }
    __syncthreads();
#pragma unroll
    for (int i = 0; i < 16; ++i) {
      int dl = ty + i * 4;
      vtbf[((size_t)bh * HD + d0 + dl) * CC + c0 + tx] = f2bf(tile[tx][dl]);
    }
  } else {                        // mask flags: flag[qt*32+ct] = any != 0
    __shared__ int s[4];
    const int e  = b - 9216;
    const int qt = e >> 5, ct = e & 31;
    const int w = t >> 6;
    const float4* m4 = (const float4*)mask;
    int nz = 0;
#pragma unroll
    for (int i = 0; i < 8; ++i) {
      int idx = i * 256 + t;
      int row = idx >> 4, c4 = idx & 15;
      float4 v = m4[(size_t)(qt * 128 + row) * (CC / 4) + ct * 16 + c4];
      nz |= (v.x != 0.f) | (v.y != 0.f) | (v.z != 0.f) | (v.w != 0.f);
    }
    int wa = (int)__any(nz);
    if ((t & 63) == 0) s[w] = wa;
    __syncthreads();
    if (t == 0) flags[qt * 32 + ct] = s[0] | s[1] | s[2] | s[3];
  }
}

// ---------------- GEMM: C[M,N] = A[M,K] * B[N,K]^T  (m97 structure + T1) ------
template <int OUT_BF16>
__global__ __launch_bounds__(256, 2) void gemm_bt(
    const unsigned short* __restrict__ A,
    const unsigned short* __restrict__ Bw,
    void* __restrict__ Cout,
    int M, int N, int K, float scale)
{
  __shared__ __align__(16) unsigned short As[128 * 32];
  __shared__ __align__(16) unsigned short Bs[128 * 32];
  const int t = threadIdx.x;
  const int w = t >> 6, lane = t & 63;
  const int wr = w >> 1, wc = w & 1;
  // XCD-chunked swizzle (nwg % 8 == 0 here -> bijective)
  const int nwg  = gridDim.x * gridDim.y;
  const int flat = blockIdx.y * gridDim.x + blockIdx.x;
  const int swzb = (flat & 7) * (nwg >> 3) + (flat >> 3);
  const int bm0 = (swzb / gridDim.x) * 128, bn0 = (swzb % gridDim.x) * 128;

  const unsigned short* aSrc = A  + (size_t)(bm0 + (t >> 2)) * K + (t & 3) * 8;
  const unsigned short* bSrc = Bw + (size_t)(bn0 + (t >> 2)) * K + (t & 3) * 8;
  char* aDst = (char*)As + w * 1024;
  char* bDst = (char*)Bs + w * 1024;
  const size_t half = (size_t)64 * K;

  f32x4 acc[4][4];
#pragma unroll
  for (int m = 0; m < 4; ++m)
#pragma unroll
    for (int n = 0; n < 4; ++n) acc[m][n] = (f32x4){0.f, 0.f, 0.f, 0.f};

  for (int k0 = 0; k0 < K; k0 += 32) {
    gl_lds16(aSrc,        aDst);
    gl_lds16(aSrc + half, aDst + 4096);
    gl_lds16(bSrc,        bDst);
    gl_lds16(bSrc + half, bDst + 4096);
    aSrc += 32; bSrc += 32;
    __syncthreads();

    bf16x8 af[4], bf[4];
#pragma unroll
    for (int m = 0; m < 4; ++m)
      af[m] = *(const bf16x8*)&As[(wr * 64 + m * 16 + (lane & 15)) * 32 + (lane >> 4) * 8];
#pragma unroll
    for (int n = 0; n < 4; ++n)
      bf[n] = *(const bf16x8*)&Bs[(wc * 64 + n * 16 + (lane & 15)) * 32 + (lane >> 4) * 8];
#pragma unroll
    for (int m = 0; m < 4; ++m)
#pragma unroll
      for (int n = 0; n < 4; ++n)
        acc[m][n] = __builtin_amdgcn_mfma_f32_16x16x32_bf16(af[m], bf[n], acc[m][n], 0, 0, 0);
    __syncthreads();
  }

  const int r0 = (lane >> 4) * 4, cl = lane & 15;
#pragma unroll
  for (int m = 0; m < 4; ++m) {
#pragma unroll
    for (int n = 0; n < 4; ++n) {
      int row = bm0 + wr * 64 + m * 16 + r0;
      int col = bn0 + wc * 64 + n * 16 + cl;
#pragma unroll
      for (int r = 0; r < 4; ++r) {
        float v = acc[m][n][r] * scale;
        if (OUT_BF16) ((unsigned short*)Cout)[(size_t)(row + r) * N + col] = f2bf(v);
        else          ((float*)Cout)[(size_t)(row + r) * N + col] = v;
      }
    }
  }
}

// ---------------- flash attention (R6 verbatim — 121us measured) ----------
// QT=128 (4 waves x 32 rows), KT=64, double-buffered K/V, log2-domain softmax,
// T13 defer-max, mask gated by per-tile nonzero flags (pipelined 1 tile ahead).
// XCD remap: logical=(bid&7)*64+(bid>>3) -> each head's 8 q-tiles + 8 heads/XCD.
__global__ __launch_bounds__(256, 2) void attn_fwd(
    const unsigned short* __restrict__ Qb,
    const unsigned short* __restrict__ Kb,
    const unsigned short* __restrict__ Vtb,
    const float* __restrict__ mask,
    const int* __restrict__ Mf,
    unsigned short* __restrict__ Ob)
{
  __shared__ __align__(16) unsigned short Ks[2][64 * 128];   // 16KB x2
  __shared__ __align__(16) unsigned short Vs[2][64 * 128];   // logical [128][64] x2
  __shared__ __align__(16) unsigned short Ps[4][32 * 64];    // 4KB/wave

  const int t = threadIdx.x, w = t >> 6, lane = t & 63;
  const int lg = (blockIdx.x & 7) * 64 + (blockIdx.x >> 3);  // XCD-chunked remap
  const int qt = lg & 7, bh = lg >> 3;
  const int hh = bh & (NH - 1), bb = bh >> 5;
  const int q0 = qt * 128;
  const int l15 = lane & 15, g = lane >> 4;
  const int rb4 = g * 4;

  // Q fragments in registers: 2 row-frags x 4 k-frags
  bf16x8 qf[2][4];
#pragma unroll
  for (int rf = 0; rf < 2; ++rf) {
    const unsigned short* qp = Qb + ((size_t)(bb * SS + q0 + w * 32 + rf * 16 + l15)) * DIM
                               + hh * HD + g * 8;
#pragma unroll
    for (int kk = 0; kk < 4; ++kk)
      qf[rf][kk] = *(const bf16x8*)(qp + kk * 32);
  }

  const unsigned short* kSrc = Kb + ((size_t)bh * CC + (t >> 4)) * HD
                               + (((t & 15) ^ ((t >> 4) & 7)) * 8);
  const unsigned short* vSrc = Vtb + ((size_t)bh * HD + (t >> 3)) * CC
                               + (((t & 7) ^ ((t >> 3) & 7)) * 8);

  f32x4 acc_o[2][8];
#pragma unroll
  for (int rf = 0; rf < 2; ++rf)
#pragma unroll
    for (int i = 0; i < 8; ++i) acc_o[rf][i] = (f32x4){0.f, 0.f, 0.f, 0.f};
  float m_run[2][4], l_run[2][4];
#pragma unroll
  for (int rf = 0; rf < 2; ++rf)
#pragma unroll
    for (int r = 0; r < 4; ++r) { m_run[rf][r] = -1e30f; l_run[rf][r] = 0.f; }

  const int swz = (lane & 7) << 3;
  const float LOG2E = 1.4426950408889634f;

  // prologue: stage tile 0 into buffer 0; flag for tile 0
  int mflag = Mf[qt * 32];
  {
    char* kd = (char*)Ks[0] + w * 1024;
    char* vd = (char*)Vs[0] + w * 1024;
#pragma unroll
    for (int i = 0; i < 4; ++i) {
      gl_lds16(kSrc + (size_t)(i * 16) * HD, kd + i * 4096);
      gl_lds16(vSrc + (size_t)i * 32 * CC,   vd + i * 4096);
    }
  }
  __syncthreads();

  int cur = 0;
  for (int c0 = 0; c0 < CC; c0 += 64) {
    const int ct = c0 >> 6;
    int nextFlag = (ct < 31) ? Mf[qt * 32 + ct + 1] : 0;

    // 1) mask loads FIRST when this tile's mask is nonzero (oldest in FIFO)
    float mk[2][4][4];
    if (mflag) {
#pragma unroll
      for (int rf = 0; rf < 2; ++rf)
#pragma unroll
        for (int nf = 0; nf < 4; ++nf)
#pragma unroll
          for (int r = 0; r < 4; ++r)
            mk[rf][nf][r] = mask[(size_t)(q0 + w * 32 + rf * 16 + rb4 + r) * CC
                                 + c0 + nf * 16 + l15];
      __builtin_amdgcn_sched_barrier(0);
    }

    // 2) stage NEXT tile (stays in flight across the whole tile)
    if (c0 + 64 < CC) {
      char* kd = (char*)Ks[cur ^ 1] + w * 1024;
      char* vd = (char*)Vs[cur ^ 1] + w * 1024;
#pragma unroll
      for (int i = 0; i < 4; ++i) {
        gl_lds16(kSrc + (size_t)(c0 + 64 + i * 16) * HD, kd + i * 4096);
        gl_lds16(vSrc + (size_t)i * 32 * CC + c0 + 64,   vd + i * 4096);
      }
    }
    __builtin_amdgcn_sched_barrier(0);

    // 3) QK^T for both row-frags (K frag read once, used twice)
    f32x4 sc[2][4];
#pragma unroll
    for (int rf = 0; rf < 2; ++rf)
#pragma unroll
      for (int nf = 0; nf < 4; ++nf) sc[rf][nf] = (f32x4){0.f, 0.f, 0.f, 0.f};
    __builtin_amdgcn_s_setprio(1);
#pragma unroll
    for (int kk = 0; kk < 4; ++kk) {
#pragma unroll
      for (int nf = 0; nf < 4; ++nf) {
        bf16x8 kf = *(const bf16x8*)&Ks[cur][((nf * 16 + l15) * 128 + kk * 32 + g * 8) ^ swz];
        sc[0][nf] = __builtin_amdgcn_mfma_f32_16x16x32_bf16(qf[0][kk], kf, sc[0][nf], 0, 0, 0);
        sc[1][nf] = __builtin_amdgcn_mfma_f32_16x16x32_bf16(qf[1][kk], kf, sc[1][nf], 0, 0, 0);
      }
    }
    __builtin_amdgcn_s_setprio(0);

    // 3b) + mask (log2 domain) — only when nonzero
    if (mflag) {
#pragma unroll
      for (int rf = 0; rf < 2; ++rf)
#pragma unroll
        for (int nf = 0; nf < 4; ++nf)
#pragma unroll
          for (int r = 0; r < 4; ++r)
            sc[rf][nf][r] = fmaf(mk[rf][nf][r], LOG2E, sc[rf][nf][r]);
    }

    // 4) softmax per row-frag (log2 domain, T13 defer-max)
#pragma unroll
    for (int rf = 0; rf < 2; ++rf) {
      int ok = 1;
      float pm[4];
#pragma unroll
      for (int r = 0; r < 4; ++r) {
        pm[r] = fmaxf(fmaxf(sc[rf][0][r], sc[rf][1][r]), fmaxf(sc[rf][2][r], sc[rf][3][r]));
        ok = ok && (pm[r] <= m_run[rf][r] + 8.0f);
      }
      if (!__all(ok)) {
#pragma unroll
        for (int r = 0; r < 4; ++r) {
          float mx = pm[r];
#pragma unroll
          for (int d = 1; d < 16; d <<= 1)
            mx = fmaxf(mx, __shfl_xor(mx, d));
          float mn = fmaxf(m_run[rf][r], mx);
          float corr = __builtin_amdgcn_exp2f(m_run[rf][r] - mn);
          m_run[rf][r] = mn;
          l_run[rf][r] *= corr;
#pragma unroll
          for (int nd = 0; nd < 8; ++nd) acc_o[rf][nd][r] *= corr;
        }
      }

#pragma unroll
      for (int r = 0; r < 4; ++r) {
        int rw = rf * 16 + rb4 + r;
        int rsw = (rw & 7) << 3;
#pragma unroll
        for (int nf = 0; nf < 4; ++nf) {
          float p = __builtin_amdgcn_exp2f(sc[rf][nf][r] - m_run[rf][r]);
          l_run[rf][r] += p;
          Ps[w][rw * 64 + ((nf * 16 + l15) ^ rsw)] = f2bf(p);
        }
      }
    }

    // 5) PV for both row-frags (V frag read once, used twice)
    __builtin_amdgcn_s_setprio(1);
#pragma unroll
    for (int kk = 0; kk < 2; ++kk) {
      bf16x8 pf0 = *(const bf16x8*)&Ps[w][((0 * 16 + l15) * 64 + kk * 32 + g * 8) ^ swz];
      bf16x8 pf1 = *(const bf16x8*)&Ps[w][((1 * 16 + l15) * 64 + kk * 32 + g * 8) ^ swz];
#pragma unroll
      for (int nd = 0; nd < 8; ++nd) {
        bf16x8 vf = *(const bf16x8*)&Vs[cur][((nd * 16 + l15) * 64 + kk * 32 + g * 8) ^ swz];
        acc_o[0][nd] = __builtin_amdgcn_mfma_f32_16x16x32_bf16(pf0, vf, acc_o[0][nd], 0, 0, 0);
        acc_o[1][nd] = __builtin_amdgcn_mfma_f32_16x16x32_bf16(pf1, vf, acc_o[1][nd], 0, 0, 0);
      }
    }
    __builtin_amdgcn_s_setprio(0);
    __syncthreads();
    cur ^= 1;
    mflag = nextFlag;
  }

  // epilogue: reduce per-lane partial l across the 16-lane row group, then O/l
#pragma unroll
  for (int rf = 0; rf < 2; ++rf) {
#pragma unroll
    for (int r = 0; r < 4; ++r)
#pragma unroll
      for (int d = 1; d < 16; d <<= 1)
        l_run[rf][r] += __shfl_xor(l_run[rf][r], d);

#pragma unroll
    for (int nd = 0; nd < 8; ++nd)
#pragma unroll
      for (int r = 0; r < 4; ++r) {
        float v = acc_o[rf][nd][r] / l_run[rf][r];
        int row = q0 + w * 32 + rf * 16 + rb4 + r;
        Ob[(size_t)(bb * SS + row) * DIM + hh * HD + nd * 16 + l15] = f2bf(v);
      }
  }
}

// ---------------- launch ----------------
extern "C" void kernel_launch(void* const* d_in, const int* in_sizes, int n_in,
                              void* d_out, int out_size, void* d_ws, size_t ws_size,
                              hipStream_t stream) {
  const float* x       = (const float*)d_in[0];
  const float* mask    = (const float*)d_in[2];   // [1,1,S,C]
  const float* cache_k = (const float*)d_in[4];   // [B,C,NH,HD]
  const float* cache_v = (const float*)d_in[5];
  const float* wq      = (const float*)d_in[6];   // [DIM,DIM]
  const float* wo      = (const float*)d_in[9];
  float* out = (float*)d_out;

  // workspace layout (128 MiB):
  char* ws = (char*)d_ws;
  unsigned short* Wbf  = (unsigned short*)(ws);                                  // 32 MiB (wq, later wo)
  unsigned short* xbf  = (unsigned short*)(ws + 33554432);                       // 16 MiB (x, later attn-out)
  unsigned short* qbf  = (unsigned short*)(ws + 33554432 + 16777216);            // 16 MiB
  unsigned short* kbf  = (unsigned short*)(ws + 33554432 + 2 * 16777216);        // 32 MiB
  unsigned short* vtbf = (unsigned short*)(ws + 2 * 33554432 + 2 * 16777216);    // 32 MiB
  // mask flags (1 KiB) at the head of d_out — final gemm overwrites all of
  // d_out afterwards, so no stale state leaks across replays.
  int* mflags = (int*)d_out;

  // one merged prep kernel: x-conv | wq-conv | k-conv | v^T | mask flags
  prep<<<9472, 256, 0, stream>>>(x, xbf, wq, Wbf, cache_k, kbf, cache_v, vtbf,
                                 mask, mflags);
  dim3 gg(DIM / 128, (BB * SS) / 128);
  // scale = (1/sqrt(128)) * log2(e) — softmax runs in log2 domain
  gemm_bt<1><<<gg, 256, 0, stream>>>(xbf, Wbf, qbf, BB * SS, DIM, DIM, 0.12751744682f);
  attn_fwd<<<BB * NH * 8, 256, 0, stream>>>(qbf, kbf, vtbf, mask, mflags, xbf);
  conv_f32_bf16<<<2048, 256, 0, stream>>>(wo, Wbf, DIM * DIM / 4);
  gemm_bt<0><<<gg, 256, 0, stream>>>(xbf, Wbf, out, BB * SS, DIM, DIM, 1.0f);
}

// Round 9
// 355.796 us; speedup vs baseline: 1.2651x; 1.0723x over previous
//
#include <hip/hip_runtime.h>
#include <hip/hip_bf16.h>
#include <stdint.h>

// Attention_48241072668890: x@Wq^T -> flash-attn over fp32 KV cache -> @Wo^T
// R9: fix R8's silent GEMM regression (129us, FETCH 141MB). (1) gemm tile
// mapping reverted to IDENTITY — the R6 m-chunked "XCD swizzle" gave each XCD
// 2 m-rows x all 32 n-tiles (no B locality, ~3x B refetch). (2) prep split by
// consumer: prep_a (x,wq converts) right before gemmQ keeps A/B L3-hot;
// prep_b (k,v^T,flags) right before attn keeps K/V hot. attn = R6 verbatim.

#define DIM   4096
#define NH    32
#define HD    128
#define BB    2
#define SS    1024
#define CC    2048

typedef __bf16 bf16x8 __attribute__((ext_vector_type(8)));
typedef float  f32x4  __attribute__((ext_vector_type(4)));

__device__ __forceinline__ unsigned short f2bf(float f) {
  union { __hip_bfloat16 h; unsigned short u; } cv;
  cv.h = __float2bfloat16(f);
  return cv.u;
}

__device__ __forceinline__ void gl_lds16(const void* g, void* l) {
  __builtin_amdgcn_global_load_lds(
      (__attribute__((address_space(1))) void*)(uintptr_t)(g),
      (__attribute__((address_space(3))) void*)(l), 16, 0, 0);
}

// ---------------- wo convert (runs post-attn; Wbf buffer reused) ----------
__global__ void conv_f32_bf16(const float* __restrict__ in, unsigned short* __restrict__ out, int n4) {
  int i = blockIdx.x * blockDim.x + threadIdx.x;
  int stride = gridDim.x * blockDim.x;
  for (; i < n4; i += stride) {
    float4 v = reinterpret_cast<const float4*>(in)[i];
    ushort4 o;
    o.x = f2bf(v.x); o.y = f2bf(v.y); o.z = f2bf(v.z); o.w = f2bf(v.w);
    reinterpret_cast<ushort4*>(out)[i] = o;
  }
}

// ---------------- prep_a: x f32->bf16 | wq f32->bf16 (feeds gemmQ) --------
// blocks [0,1024): x (2.09M float4, 8/thread)
// blocks [1024,3072): wq (4.19M float4, 8/thread)
__global__ __launch_bounds__(256) void prep_a(
    const float* __restrict__ x,  unsigned short* __restrict__ xbf,
    const float* __restrict__ wq, unsigned short* __restrict__ wbf)
{
  const int b = blockIdx.x, t = threadIdx.x;
  const float* in; unsigned short* out; int base, nthr, n4;
  if (b < 1024) { in = x;  out = xbf; base = b;        nthr = 1024 * 256; n4 = BB * SS * DIM / 4; }
  else          { in = wq; out = wbf; base = b - 1024; nthr = 2048 * 256; n4 = DIM * DIM / 4; }
  for (int i = base * 256 + t; i < n4; i += nthr) {
    float4 v = reinterpret_cast<const float4*>(in)[i];
    ushort4 o;
    o.x = f2bf(v.x); o.y = f2bf(v.y); o.z = f2bf(v.z); o.w = f2bf(v.w);
    reinterpret_cast<ushort4*>(out)[i] = o;
  }
}

// ---------------- prep_b: k-conv | v^T | mask flags (feeds attn) ----------
// blocks [0,2048): cache_k gather; [2048,6144): cache_v 64x64 transpose;
// [6144,6400): mask nonzero flags (128q x 64c).
__global__ __launch_bounds__(256) void prep_b(
    const float* __restrict__ ck,  unsigned short* __restrict__ kbf,
    const float* __restrict__ cv,  unsigned short* __restrict__ vtbf,
    const float* __restrict__ mask, int* __restrict__ flags)
{
  const int b = blockIdx.x, t = threadIdx.x;

  if (b < 2048) {                 // cache_k [B,C,NH,HD] -> [B*NH,C,HD] bf16
    const int total4 = BB * NH * CC * HD / 4;
    for (int i = b * 256 + t; i < total4; i += 2048 * 256) {
      size_t o = (size_t)i * 4;
      int d  = (int)(o & (HD - 1));
      size_t r = o >> 7;
      int c  = (int)(r & (CC - 1));
      int bh = (int)(r >> 11);
      int hh = bh & (NH - 1), bb = bh >> 5;
      float4 v = *reinterpret_cast<const float4*>(ck + ((size_t)(bb * CC + c) * NH + hh) * HD + d);
      ushort4 u; u.x = f2bf(v.x); u.y = f2bf(v.y); u.z = f2bf(v.z); u.w = f2bf(v.w);
      *reinterpret_cast<ushort4*>(kbf + o) = u;
    }
  } else if (b < 6144) {          // cache_v [B,C,NH,HD] -> [B*NH,HD,C] bf16
    __shared__ float tile[64][65];
    const int e  = b - 2048;
    const int ct = e & 31, rest = e >> 5;
    const int dt = rest & 1, bh = rest >> 1;
    const int hh = bh & (NH - 1), bb = bh >> 5;
    const int c0 = ct * 64, d0 = dt * 64;
    const int tx = t & 63, ty = t >> 6;           // 64 x 4
#pragma unroll
    for (int i = 0; i < 16; ++i) {
      int cl = ty + i * 4;
      tile[cl][tx] = cv[((size_t)(bb * CC + c0 + cl) * NH + hh) * HD + d0 + tx];
    }
    __syncthreads();
#pragma unroll
    for (int i = 0; i < 16; ++i) {
      int dl = ty + i * 4;
      vtbf[((size_t)bh * HD + d0 + dl) * CC + c0 + tx] = f2bf(tile[tx][dl]);
    }
  } else {                        // mask flags: flag[qt*32+ct] = any != 0
    __shared__ int s[4];
    const int e  = b - 6144;
    const int qt = e >> 5, ct = e & 31;
    const int w = t >> 6;
    const float4* m4 = (const float4*)mask;
    int nz = 0;
#pragma unroll
    for (int i = 0; i < 8; ++i) {
      int idx = i * 256 + t;
      int row = idx >> 4, c4 = idx & 15;
      float4 v = m4[(size_t)(qt * 128 + row) * (CC / 4) + ct * 16 + c4];
      nz |= (v.x != 0.f) | (v.y != 0.f) | (v.z != 0.f) | (v.w != 0.f);
    }
    int wa = (int)__any(nz);
    if ((t & 63) == 0) s[w] = wa;
    __syncthreads();
    if (t == 0) flags[qt * 32 + ct] = s[0] | s[1] | s[2] | s[3];
  }
}

// ---------------- GEMM: C[M,N] = A[M,K] * B[N,K]^T  (m97, identity map) ----
template <int OUT_BF16>
__global__ __launch_bounds__(256, 2) void gemm_bt(
    const unsigned short* __restrict__ A,
    const unsigned short* __restrict__ Bw,
    void* __restrict__ Cout,
    int M, int N, int K, float scale)
{
  __shared__ __align__(16) unsigned short As[128 * 32];
  __shared__ __align__(16) unsigned short Bs[128 * 32];
  const int t = threadIdx.x;
  const int w = t >> 6, lane = t & 63;
  const int wr = w >> 1, wc = w & 1;
  // identity tile mapping (R6's m-chunked swizzle killed B locality: 141MB fetch)
  const int bm0 = blockIdx.y * 128, bn0 = blockIdx.x * 128;

  const unsigned short* aSrc = A  + (size_t)(bm0 + (t >> 2)) * K + (t & 3) * 8;
  const unsigned short* bSrc = Bw + (size_t)(bn0 + (t >> 2)) * K + (t & 3) * 8;
  char* aDst = (char*)As + w * 1024;
  char* bDst = (char*)Bs + w * 1024;
  const size_t half = (size_t)64 * K;

  f32x4 acc[4][4];
#pragma unroll
  for (int m = 0; m < 4; ++m)
#pragma unroll
    for (int n = 0; n < 4; ++n) acc[m][n] = (f32x4){0.f, 0.f, 0.f, 0.f};

  for (int k0 = 0; k0 < K; k0 += 32) {
    gl_lds16(aSrc,        aDst);
    gl_lds16(aSrc + half, aDst + 4096);
    gl_lds16(bSrc,        bDst);
    gl_lds16(bSrc + half, bDst + 4096);
    aSrc += 32; bSrc += 32;
    __syncthreads();

    bf16x8 af[4], bf[4];
#pragma unroll
    for (int m = 0; m < 4; ++m)
      af[m] = *(const bf16x8*)&As[(wr * 64 + m * 16 + (lane & 15)) * 32 + (lane >> 4) * 8];
#pragma unroll
    for (int n = 0; n < 4; ++n)
      bf[n] = *(const bf16x8*)&Bs[(wc * 64 + n * 16 + (lane & 15)) * 32 + (lane >> 4) * 8];
#pragma unroll
    for (int m = 0; m < 4; ++m)
#pragma unroll
      for (int n = 0; n < 4; ++n)
        acc[m][n] = __builtin_amdgcn_mfma_f32_16x16x32_bf16(af[m], bf[n], acc[m][n], 0, 0, 0);
    __syncthreads();
  }

  const int r0 = (lane >> 4) * 4, cl = lane & 15;
#pragma unroll
  for (int m = 0; m < 4; ++m) {
#pragma unroll
    for (int n = 0; n < 4; ++n) {
      int row = bm0 + wr * 64 + m * 16 + r0;
      int col = bn0 + wc * 64 + n * 16 + cl;
#pragma unroll
      for (int r = 0; r < 4; ++r) {
        float v = acc[m][n][r] * scale;
        if (OUT_BF16) ((unsigned short*)Cout)[(size_t)(row + r) * N + col] = f2bf(v);
        else          ((float*)Cout)[(size_t)(row + r) * N + col] = v;
      }
    }
  }
}

// ---------------- flash attention (R6 verbatim — measured 121us) ----------
__global__ __launch_bounds__(256, 2) void attn_fwd(
    const unsigned short* __restrict__ Qb,
    const unsigned short* __restrict__ Kb,
    const unsigned short* __restrict__ Vtb,
    const float* __restrict__ mask,
    const int* __restrict__ Mf,
    unsigned short* __restrict__ Ob)
{
  __shared__ __align__(16) unsigned short Ks[2][64 * 128];   // 16KB x2
  __shared__ __align__(16) unsigned short Vs[2][64 * 128];   // logical [128][64] x2
  __shared__ __align__(16) unsigned short Ps[4][32 * 64];    // 4KB/wave

  const int t = threadIdx.x, w = t >> 6, lane = t & 63;
  const int lg = (blockIdx.x & 7) * 64 + (blockIdx.x >> 3);  // XCD-chunked remap
  const int qt = lg & 7, bh = lg >> 3;
  const int hh = bh & (NH - 1), bb = bh >> 5;
  const int q0 = qt * 128;
  const int l15 = lane & 15, g = lane >> 4;
  const int rb4 = g * 4;

  // Q fragments in registers: 2 row-frags x 4 k-frags
  bf16x8 qf[2][4];
#pragma unroll
  for (int rf = 0; rf < 2; ++rf) {
    const unsigned short* qp = Qb + ((size_t)(bb * SS + q0 + w * 32 + rf * 16 + l15)) * DIM
                               + hh * HD + g * 8;
#pragma unroll
    for (int kk = 0; kk < 4; ++kk)
      qf[rf][kk] = *(const bf16x8*)(qp + kk * 32);
  }

  const unsigned short* kSrc = Kb + ((size_t)bh * CC + (t >> 4)) * HD
                               + (((t & 15) ^ ((t >> 4) & 7)) * 8);
  const unsigned short* vSrc = Vtb + ((size_t)bh * HD + (t >> 3)) * CC
                               + (((t & 7) ^ ((t >> 3) & 7)) * 8);

  f32x4 acc_o[2][8];
#pragma unroll
  for (int rf = 0; rf < 2; ++rf)
#pragma unroll
    for (int i = 0; i < 8; ++i) acc_o[rf][i] = (f32x4){0.f, 0.f, 0.f, 0.f};
  float m_run[2][4], l_run[2][4];
#pragma unroll
  for (int rf = 0; rf < 2; ++rf)
#pragma unroll
    for (int r = 0; r < 4; ++r) { m_run[rf][r] = -1e30f; l_run[rf][r] = 0.f; }

  const int swz = (lane & 7) << 3;
  const float LOG2E = 1.4426950408889634f;

  // prologue: stage tile 0 into buffer 0; flag for tile 0
  int mflag = Mf[qt * 32];
  {
    char* kd = (char*)Ks[0] + w * 1024;
    char* vd = (char*)Vs[0] + w * 1024;
#pragma unroll
    for (int i = 0; i < 4; ++i) {
      gl_lds16(kSrc + (size_t)(i * 16) * HD, kd + i * 4096);
      gl_lds16(vSrc + (size_t)i * 32 * CC,   vd + i * 4096);
    }
  }
  __syncthreads();

  int cur = 0;
  for (int c0 = 0; c0 < CC; c0 += 64) {
    const int ct = c0 >> 6;
    int nextFlag = (ct < 31) ? Mf[qt * 32 + ct + 1] : 0;

    // 1) mask loads FIRST when this tile's mask is nonzero (oldest in FIFO)
    float mk[2][4][4];
    if (mflag) {
#pragma unroll
      for (int rf = 0; rf < 2; ++rf)
#pragma unroll
        for (int nf = 0; nf < 4; ++nf)
#pragma unroll
          for (int r = 0; r < 4; ++r)
            mk[rf][nf][r] = mask[(size_t)(q0 + w * 32 + rf * 16 + rb4 + r) * CC
                                 + c0 + nf * 16 + l15];
      __builtin_amdgcn_sched_barrier(0);
    }

    // 2) stage NEXT tile (stays in flight across the whole tile)
    if (c0 + 64 < CC) {
      char* kd = (char*)Ks[cur ^ 1] + w * 1024;
      char* vd = (char*)Vs[cur ^ 1] + w * 1024;
#pragma unroll
      for (int i = 0; i < 4; ++i) {
        gl_lds16(kSrc + (size_t)(c0 + 64 + i * 16) * HD, kd + i * 4096);
        gl_lds16(vSrc + (size_t)i * 32 * CC + c0 + 64,   vd + i * 4096);
      }
    }
    __builtin_amdgcn_sched_barrier(0);

    // 3) QK^T for both row-frags (K frag read once, used twice)
    f32x4 sc[2][4];
#pragma unroll
    for (int rf = 0; rf < 2; ++rf)
#pragma unroll
      for (int nf = 0; nf < 4; ++nf) sc[rf][nf] = (f32x4){0.f, 0.f, 0.f, 0.f};
    __builtin_amdgcn_s_setprio(1);
#pragma unroll
    for (int kk = 0; kk < 4; ++kk) {
#pragma unroll
      for (int nf = 0; nf < 4; ++nf) {
        bf16x8 kf = *(const bf16x8*)&Ks[cur][((nf * 16 + l15) * 128 + kk * 32 + g * 8) ^ swz];
        sc[0][nf] = __builtin_amdgcn_mfma_f32_16x16x32_bf16(qf[0][kk], kf, sc[0][nf], 0, 0, 0);
        sc[1][nf] = __builtin_amdgcn_mfma_f32_16x16x32_bf16(qf[1][kk], kf, sc[1][nf], 0, 0, 0);
      }
    }
    __builtin_amdgcn_s_setprio(0);

    // 3b) + mask (log2 domain) — only when nonzero
    if (mflag) {
#pragma unroll
      for (int rf = 0; rf < 2; ++rf)
#pragma unroll
        for (int nf = 0; nf < 4; ++nf)
#pragma unroll
          for (int r = 0; r < 4; ++r)
            sc[rf][nf][r] = fmaf(mk[rf][nf][r], LOG2E, sc[rf][nf][r]);
    }

    // 4) softmax per row-frag (log2 domain, T13 defer-max)
#pragma unroll
    for (int rf = 0; rf < 2; ++rf) {
      int ok = 1;
      float pm[4];
#pragma unroll
      for (int r = 0; r < 4; ++r) {
        pm[r] = fmaxf(fmaxf(sc[rf][0][r], sc[rf][1][r]), fmaxf(sc[rf][2][r], sc[rf][3][r]));
        ok = ok && (pm[r] <= m_run[rf][r] + 8.0f);
      }
      if (!__all(ok)) {
#pragma unroll
        for (int r = 0; r < 4; ++r) {
          float mx = pm[r];
#pragma unroll
          for (int d = 1; d < 16; d <<= 1)
            mx = fmaxf(mx, __shfl_xor(mx, d));
          float mn = fmaxf(m_run[rf][r], mx);
          float corr = __builtin_amdgcn_exp2f(m_run[rf][r] - mn);
          m_run[rf][r] = mn;
          l_run[rf][r] *= corr;
#pragma unroll
          for (int nd = 0; nd < 8; ++nd) acc_o[rf][nd][r] *= corr;
        }
      }

#pragma unroll
      for (int r = 0; r < 4; ++r) {
        int rw = rf * 16 + rb4 + r;
        int rsw = (rw & 7) << 3;
#pragma unroll
        for (int nf = 0; nf < 4; ++nf) {
          float p = __builtin_amdgcn_exp2f(sc[rf][nf][r] - m_run[rf][r]);
          l_run[rf][r] += p;
          Ps[w][rw * 64 + ((nf * 16 + l15) ^ rsw)] = f2bf(p);
        }
      }
    }

    // 5) PV for both row-frags (V frag read once, used twice)
    __builtin_amdgcn_s_setprio(1);
#pragma unroll
    for (int kk = 0; kk < 2; ++kk) {
      bf16x8 pf0 = *(const bf16x8*)&Ps[w][((0 * 16 + l15) * 64 + kk * 32 + g * 8) ^ swz];
      bf16x8 pf1 = *(const bf16x8*)&Ps[w][((1 * 16 + l15) * 64 + kk * 32 + g * 8) ^ swz];
#pragma unroll
      for (int nd = 0; nd < 8; ++nd) {
        bf16x8 vf = *(const bf16x8*)&Vs[cur][((nd * 16 + l15) * 64 + kk * 32 + g * 8) ^ swz];
        acc_o[0][nd] = __builtin_amdgcn_mfma_f32_16x16x32_bf16(pf0, vf, acc_o[0][nd], 0, 0, 0);
        acc_o[1][nd] = __builtin_amdgcn_mfma_f32_16x16x32_bf16(pf1, vf, acc_o[1][nd], 0, 0, 0);
      }
    }
    __builtin_amdgcn_s_setprio(0);
    __syncthreads();
    cur ^= 1;
    mflag = nextFlag;
  }

  // epilogue: reduce per-lane partial l across the 16-lane row group, then O/l
#pragma unroll
  for (int rf = 0; rf < 2; ++rf) {
#pragma unroll
    for (int r = 0; r < 4; ++r)
#pragma unroll
      for (int d = 1; d < 16; d <<= 1)
        l_run[rf][r] += __shfl_xor(l_run[rf][r], d);

#pragma unroll
    for (int nd = 0; nd < 8; ++nd)
#pragma unroll
      for (int r = 0; r < 4; ++r) {
        float v = acc_o[rf][nd][r] / l_run[rf][r];
        int row = q0 + w * 32 + rf * 16 + rb4 + r;
        Ob[(size_t)(bb * SS + row) * DIM + hh * HD + nd * 16 + l15] = f2bf(v);
      }
  }
}

// ---------------- launch ----------------
extern "C" void kernel_launch(void* const* d_in, const int* in_sizes, int n_in,
                              void* d_out, int out_size, void* d_ws, size_t ws_size,
                              hipStream_t stream) {
  const float* x       = (const float*)d_in[0];
  const float* mask    = (const float*)d_in[2];   // [1,1,S,C]
  const float* cache_k = (const float*)d_in[4];   // [B,C,NH,HD]
  const float* cache_v = (const float*)d_in[5];
  const float* wq      = (const float*)d_in[6];   // [DIM,DIM]
  const float* wo      = (const float*)d_in[9];
  float* out = (float*)d_out;

  // workspace layout (128 MiB):
  char* ws = (char*)d_ws;
  unsigned short* Wbf  = (unsigned short*)(ws);                                  // 32 MiB (wq, later wo)
  unsigned short* xbf  = (unsigned short*)(ws + 33554432);                       // 16 MiB (x, later attn-out)
  unsigned short* qbf  = (unsigned short*)(ws + 33554432 + 16777216);            // 16 MiB
  unsigned short* kbf  = (unsigned short*)(ws + 33554432 + 2 * 16777216);        // 32 MiB
  unsigned short* vtbf = (unsigned short*)(ws + 2 * 33554432 + 2 * 16777216);    // 32 MiB
  // mask flags (1 KiB) at the head of d_out — final gemm overwrites all of
  // d_out afterwards, so no stale state leaks across replays.
  int* mflags = (int*)d_out;

  dim3 gg(DIM / 128, (BB * SS) / 128);
  // prep_a feeds gemmQ (A/B stay L3-hot); scale = (1/sqrt(128))*log2(e)
  prep_a<<<3072, 256, 0, stream>>>(x, xbf, wq, Wbf);
  gemm_bt<1><<<gg, 256, 0, stream>>>(xbf, Wbf, qbf, BB * SS, DIM, DIM, 0.12751744682f);
  // prep_b feeds attn (K/V/flags stay hot)
  prep_b<<<6400, 256, 0, stream>>>(cache_k, kbf, cache_v, vtbf, mask, mflags);
  attn_fwd<<<BB * NH * 8, 256, 0, stream>>>(qbf, kbf, vtbf, mask, mflags, xbf);
  conv_f32_bf16<<<2048, 256, 0, stream>>>(wo, Wbf, DIM * DIM / 4);
  gemm_bt<0><<<gg, 256, 0, stream>>>(xbf, Wbf, out, BB * SS, DIM, DIM, 1.0f);
}